// Round 8
// baseline (177.037 us; speedup 1.0000x reference)
//
#include <hip/hip_runtime.h>
#include <math.h>

// Problem: [16,1,1024,1024] fp32 pred/target -> scalar weighted mean-abs curvature loss.
// R8 = R7 (pred/target packed in f2v lanes, 1 col/thread, VGPR 64) + two latency fixes:
//  1) one overlapping 4B-aligned dwordx4 per array per row (3 taps in one load;
//     was 6 scalar loads) -- R5 precedent for align(4) f4 loads.
//  2) explicit 1-iteration software pipeline: loads for row i+2 issue before the
//     basis+curv of row i, so the s_waitcnt lands ~270 VALU cycles after issue.
// Edge columns handled by MODE-templated extraction (interior tiles: zero selects).
// Numerics identical to R5/R6/R7 (all passed absmax 0.0): reference EPS kept in
// den_p/den_l (R2 lesson), mean-denom EPS below half-ulp of 2 -> folded into
// weight (0.2 -> 0.1), shared rcp(den_p*den_l). R4 lesson: no min-waves bound.

constexpr int IMG_B = 16;
constexpr int IMG_H = 1024;
constexpr int IMG_W = 1024;
constexpr int ROWS  = 16;                      // rows per block
constexpr int BLOCK = 256;                     // 256 threads = 256 columns
constexpr int TILES_X = IMG_W / BLOCK;         // 4
constexpr int TILES_Y = IMG_H / ROWS;          // 64
constexpr int NBLOCKS = IMG_B * TILES_Y * TILES_X;  // 4096
constexpr float EPS = 1e-8f;

// scale constants: p = gx/80, q = gy/80, r = rxx/300, 2s = sxy/200, t = tyy/300
constexpr float A2 = 1.0f / 6400.0f;
constexpr float Bc = 1.0f / 300.0f;
constexpr float C2 = 1.0f / 200.0f;

typedef float f2v __attribute__((ext_vector_type(2)));
typedef float f4v __attribute__((ext_vector_type(4), aligned(4)));  // 4B-aligned ok

__device__ __forceinline__ f2v pk_fma(f2v a, f2v b, f2v c) {
    return __builtin_elementwise_fma(a, b, c);
}

// rolling-window row state, lanes = {pred, target}
struct Rowv { f2v hx, hs, rs; };

// MODE: 0 = leftmost x-tile (lane x==0 is image edge), 1 = interior, 2 = rightmost.
// Raw f4 covers columns [cload .. cload+3]; interior: cload = x-1 -> taps at .x,.y,.z.
// MODE0 edge lane (x=0, cload=0):   w0=0,   w1=L.x, w2=L.y.
// MODE2 edge lane (x=1023,cl=1020): w0=L.z, w1=L.w, w2=0.
template<int MODE>
__device__ __forceinline__ void basis(const f4v& Lp, const f4v& Lt, bool vld, bool edge,
                                      Rowv& o)
{
    if (vld) {                                  // block-uniform branch
        float p0, p1, p2, t0, t1, t2;
        if (MODE == 1) {
            p0 = Lp.x; p1 = Lp.y; p2 = Lp.z;
            t0 = Lt.x; t1 = Lt.y; t2 = Lt.z;
        } else if (MODE == 0) {
            p0 = edge ? 0.0f : Lp.x;  p1 = edge ? Lp.x : Lp.y;  p2 = edge ? Lp.y : Lp.z;
            t0 = edge ? 0.0f : Lt.x;  t1 = edge ? Lt.x : Lt.y;  t2 = edge ? Lt.y : Lt.z;
        } else {
            p0 = edge ? Lp.z : Lp.x;  p1 = edge ? Lp.w : Lp.y;  p2 = edge ? 0.0f : Lp.z;
            t0 = edge ? Lt.z : Lt.x;  t1 = edge ? Lt.w : Lt.y;  t2 = edge ? 0.0f : Lt.z;
        }
        const f2v w0 = {p0, t0}, w1 = {p1, t1}, w2 = {p2, t2};
        const f2v e = w0 + w2;
        o.hx = w2 - w0;
        o.hs = pk_fma(f2v{2.0f, 2.0f}, w1, e);
        o.rs = e + w1;
    } else {                                    // zero 'SAME' padding row
        o.hx = f2v{0.0f, 0.0f}; o.hs = f2v{0.0f, 0.0f}; o.rs = f2v{0.0f, 0.0f};
    }
}

// prof/plan true scale; mean2 = 2*mean (weight absorbs the 1/2). Lane-parallel
// over {pred, target}; transcendentals + flat-mask per-component.
__device__ __forceinline__ void curv_pair(const Rowv& a, const Rowv& b, const Rowv& c,
                                          f2v& prof, f2v& plan, f2v& mean2)
{
    const f2v A2f = {A2, A2}, Bcf = {Bc, Bc}, C2f = {C2, C2};
    const f2v m3  = {-3.0f, -3.0f}, two = {2.0f, 2.0f};
    const f2v epsf = {EPS, EPS};

    const f2v gx  = pk_fma(two, b.hx, a.hx + c.hx);   // sobel_x (raw)
    const f2v gy  = c.hs - a.hs;                      // sobel_y (raw)
    const f2v tot = (a.rs + c.rs) + b.rs;             // 3x3 sum
    const f2v H   = (a.hs + c.hs) + b.hs;
    const f2v rxx = pk_fma(m3, H - tot, tot);         // k_xx * 3 (raw)
    const f2v tyy = pk_fma(m3, b.rs, tot);            // k_yy * 3 (raw)
    const f2v sxy = a.hx - c.hx;                      // k_xy * 4 (raw)

    const f2v gx2 = gx * gx, gy2 = gy * gy, gxgy = gx * gy;
    const f2v g2  = gx2 + gy2;
    const f2v d1  = A2f * g2;                         // p^2 + q^2
    const f2v od  = d1 + f2v{1.0f, 1.0f};

    f2v rsq_od, sq_d1;                                // per-component transcendentals
    rsq_od.x = __builtin_amdgcn_rsqf(od.x);
    rsq_od.y = __builtin_amdgcn_rsqf(od.y);
    sq_d1.x  = __builtin_amdgcn_sqrtf(d1.x);
    sq_d1.y  = __builtin_amdgcn_sqrtf(d1.y);
    const f2v sq_od = od * rsq_od;                    // sqrt(1+d1)

    const f2v h1    = pk_fma(tyy, gy2, rxx * gx2);
    const f2v h3    = pk_fma(tyy, gx2, rxx * gy2);
    const f2v h2c   = C2f * (sxy * gxgy);
    const f2v nprof = A2f * pk_fma(Bcf, h1,  h2c);    // r*p2+2s*pq+t*q2
    const f2v nplan = A2f * pk_fma(Bcf, h3, -h2c);    // r*q2-2s*pq+t*p2
    const f2v mnum  = pk_fma(Bcf, rxx + tyy, nplan);  // (1+q2)r-2pq*s+(1+p2)t

    const f2v den_p = pk_fma(d1, sq_od, epsf);        // d1*sqrt(1+d1)+EPS
    const f2v den_l = pk_fma(d1, sq_d1, epsf);        // d1^1.5+EPS
    const f2v plprod = den_p * den_l;                 // >=1e-16, no underflow
    f2v rcpPL;
    rcpPL.x = __builtin_amdgcn_rcpf(plprod.x);
    rcpPL.y = __builtin_amdgcn_rcpf(plprod.y);

    prof  = (nprof * den_l) * rcpPL;
    plan  = (nplan * den_p) * rcpPL;
    mean2 = mnum * ((rsq_od * rsq_od) * rsq_od);      // mnum/od^1.5 = 2*mean
    // flat mask per component
    prof.x = (d1.x < EPS) ? 0.0f : prof.x;
    prof.y = (d1.y < EPS) ? 0.0f : prof.y;
    plan.x = (d1.x < EPS) ? 0.0f : plan.x;
    plan.y = (d1.y < EPS) ? 0.0f : plan.y;
}

template<int MODE>
__device__ __forceinline__ float run_col(const char* __restrict__ Pc,
                                         const char* __restrict__ Tc,
                                         int y0, int cbyte, bool edge)
{
    // clamped-row raw load (address always valid; semantics fixed by vld in basis)
    auto ld = [&](const char* __restrict__ A, int y) -> f4v {
        int yc = y < 0 ? 0 : (y > IMG_H - 1 ? IMG_H - 1 : y);   // uniform SALU clamp
        return *reinterpret_cast<const f4v*>(A + (((size_t)yc << 12) + cbyte));
    };

    // software pipeline: cur = raw row about to enter the window, next = in flight
    f4v cp = ld(Pc, y0 - 1), ct = ld(Tc, y0 - 1);
    f4v np = ld(Pc, y0),     nt = ld(Tc, y0);
    Rowv w[3];
    basis<MODE>(cp, ct, y0 - 1 >= 0, edge, w[0]);
    cp = np; ct = nt;
    np = ld(Pc, y0 + 1); nt = ld(Tc, y0 + 1);
    basis<MODE>(cp, ct, true, edge, w[1]);            // row y0 always valid
    cp = np; ct = nt;

    float acc = 0.0f;
#pragma unroll
    for (int i = 0; i < ROWS; ++i) {
        const int ia = i % 3, ib = (i + 1) % 3, ic = (i + 2) % 3;
        np = ld(Pc, y0 + i + 2); nt = ld(Tc, y0 + i + 2);   // prefetch row i+2
        basis<MODE>(cp, ct, y0 + i + 1 < IMG_H, edge, w[ic]); // consume row i+1
        f2v prof, plan, mean2;
        curv_pair(w[ia], w[ib], w[ic], prof, plan, mean2);
        acc = fmaf(0.5f, fabsf(prof.x  - prof.y),  acc);
        acc = fmaf(0.3f, fabsf(plan.x  - plan.y),  acc);
        acc = fmaf(0.1f, fabsf(mean2.x - mean2.y), acc);  // 0.2*|dMean|
        cp = np; ct = nt;
    }
    return acc;
}

__global__ __launch_bounds__(BLOCK) void curv_loss_main(
    const float* __restrict__ pred, const float* __restrict__ targ,
    float* __restrict__ blocksums)
{
    const int tid = threadIdx.x;
    const int b   = blockIdx.x;
    const int tx  = b & (TILES_X - 1);
    const int ty  = (b >> 2) & (TILES_Y - 1);
    const int img = b >> 8;                   // 4*64 = 256 blocks per image
    const int y0  = ty * ROWS;
    const int x   = tx * BLOCK + tid;

    const size_t ibase = (size_t)img * (size_t)(IMG_H * IMG_W);
    const char* __restrict__ Pc = (const char*)(pred + ibase);
    const char* __restrict__ Tc = (const char*)(targ + ibase);

    int cload = x - 1;
    if (cload < 0) cload = 0;                     // only lane x==0 (MODE0 edge)
    if (cload > IMG_W - 4) cload = IMG_W - 4;     // only lane x==1023 (MODE2 edge)
    const int cbyte = cload << 2;
    const bool edge = (tx == 0) ? (tid == 0) : (tid == BLOCK - 1);

    float acc;
    if      (tx == 0)            acc = run_col<0>(Pc, Tc, y0, cbyte, edge);
    else if (tx == TILES_X - 1)  acc = run_col<2>(Pc, Tc, y0, cbyte, edge);
    else                         acc = run_col<1>(Pc, Tc, y0, cbyte, false);

    // wave64 reduce, then cross-wave via LDS
#pragma unroll
    for (int off = 32; off > 0; off >>= 1) acc += __shfl_down(acc, off, 64);
    __shared__ float ws[BLOCK / 64];
    const int lane = tid & 63, wid = tid >> 6;
    if (lane == 0) ws[wid] = acc;
    __syncthreads();
    if (tid == 0)
        blocksums[b] = (ws[0] + ws[1]) + (ws[2] + ws[3]);
}

__global__ __launch_bounds__(BLOCK) void curv_loss_final(
    const float* __restrict__ blocksums, float* __restrict__ out)
{
    const int tid = threadIdx.x;
    float v = 0.0f;
#pragma unroll
    for (int i = 0; i < NBLOCKS / BLOCK; ++i) v += blocksums[i * BLOCK + tid];
#pragma unroll
    for (int off = 32; off > 0; off >>= 1) v += __shfl_down(v, off, 64);
    __shared__ float ws[BLOCK / 64];
    const int lane = tid & 63, wid = tid >> 6;
    if (lane == 0) ws[wid] = v;
    __syncthreads();
    if (tid == 0) {
        const float tot = (ws[0] + ws[1]) + (ws[2] + ws[3]);
        out[0] = tot * (1.0f / (float)(IMG_B * IMG_H * IMG_W));
    }
}

extern "C" void kernel_launch(void* const* d_in, const int* in_sizes, int n_in,
                              void* d_out, int out_size, void* d_ws, size_t ws_size,
                              hipStream_t stream)
{
    const float* pred = (const float*)d_in[0];
    const float* targ = (const float*)d_in[1];
    float* out = (float*)d_out;
    float* blocksums = (float*)d_ws;   // 4096 floats; every slot written each call

    curv_loss_main<<<NBLOCKS, BLOCK, 0, stream>>>(pred, targ, blocksums);
    curv_loss_final<<<1, BLOCK, 0, stream>>>(blocksums, out);
}

// Round 9
// 159.124 us; speedup vs baseline: 1.1126x; 1.1126x over previous
//
#include <hip/hip_runtime.h>
#include <math.h>

// Problem: [16,1,1024,1024] fp32 pred/target -> scalar weighted mean-abs curvature loss.
// R9 = R7 (best: 57us; pred/target packed in f2v lanes, 1 col/thread, 6 scalar
// loads/row) with register pressure squeezed below the vgpr=64 wave-allocation
// cliff (m69):
//  - ONE offset VGPR per thread: vo = cbyte + (y<<12); taps load at imm +0/+4/+8
//    from a clamped base column (R7 kept 3 per-tap offsets + 6 adds/row).
//  - Edge cndmasks only in MODE0/MODE2 x-tiles (R7 paid them in every block).
//  - No software pipeline (R8: +20 VGPR, busy 42%), no min-waves bound (R4: spill).
// Cross-round law: issue volume pinned ~33us since R6; dur tracks VGPR/occupancy.
// Numerics identical to R5..R8 (all absmax 0.0): reference EPS kept in den_p/den_l
// (R2 lesson), mean-denom EPS below half-ulp of 2 -> folded into weight (0.2->0.1),
// shared rcp(den_p*den_l).

constexpr int IMG_B = 16;
constexpr int IMG_H = 1024;
constexpr int IMG_W = 1024;
constexpr int ROWS  = 16;                      // rows per block
constexpr int BLOCK = 256;                     // 256 threads = 256 columns
constexpr int TILES_X = IMG_W / BLOCK;         // 4
constexpr int TILES_Y = IMG_H / ROWS;          // 64
constexpr int NBLOCKS = IMG_B * TILES_Y * TILES_X;  // 4096
constexpr float EPS = 1e-8f;

// scale constants: p = gx/80, q = gy/80, r = rxx/300, 2s = sxy/200, t = tyy/300
constexpr float A2 = 1.0f / 6400.0f;
constexpr float Bc = 1.0f / 300.0f;
constexpr float C2 = 1.0f / 200.0f;

typedef float f2v __attribute__((ext_vector_type(2)));

__device__ __forceinline__ f2v pk_fma(f2v a, f2v b, f2v c) {
    return __builtin_elementwise_fma(a, b, c);
}

// rolling-window row state, lanes = {pred, target}
struct Rowv { f2v hx, hs, rs; };

// Taps loaded from clamped base column cb = clamp(x-1, 0, 1021):
//   interior lane: (m,c,p) = cols (x-1, x, x+1) directly.
//   MODE0 edge lane (x=0,    cb=0):    want w0=0,  w1=v[0]=m, w2=v[1]=c.
//   MODE2 edge lane (x=1023, cb=1021): want w0=v[1022]=c, w1=v[1023]=p, w2=0.
template<int MODE>
__device__ __forceinline__ void basis(float pm, float pc, float pp,
                                      float tm, float tc, float tp,
                                      bool vld, bool edge, Rowv& o)
{
    if (vld) {                                  // block-uniform branch
        f2v w0, w1, w2;
        if (MODE == 0) {
            w0 = f2v{edge ? 0.0f : pm, edge ? 0.0f : tm};
            w1 = f2v{edge ? pm : pc,   edge ? tm : tc};
            w2 = f2v{edge ? pc : pp,   edge ? tc : tp};
        } else if (MODE == 2) {
            w0 = f2v{edge ? pc : pm,   edge ? tc : tm};
            w1 = f2v{edge ? pp : pc,   edge ? tp : tc};
            w2 = f2v{edge ? 0.0f : pp, edge ? 0.0f : tp};
        } else {
            w0 = f2v{pm, tm}; w1 = f2v{pc, tc}; w2 = f2v{pp, tp};
        }
        const f2v e = w0 + w2;
        o.hx = w2 - w0;
        o.hs = pk_fma(f2v{2.0f, 2.0f}, w1, e);
        o.rs = e + w1;
    } else {                                    // zero 'SAME' padding row
        o.hx = f2v{0.0f, 0.0f}; o.hs = f2v{0.0f, 0.0f}; o.rs = f2v{0.0f, 0.0f};
    }
}

// prof/plan true scale; mean2 = 2*mean (weight absorbs the 1/2). Lane-parallel
// over {pred, target}; transcendentals + flat-mask per-component.
__device__ __forceinline__ void curv_pair(const Rowv& a, const Rowv& b, const Rowv& c,
                                          f2v& prof, f2v& plan, f2v& mean2)
{
    const f2v A2f = {A2, A2}, Bcf = {Bc, Bc}, C2f = {C2, C2};
    const f2v m3  = {-3.0f, -3.0f}, two = {2.0f, 2.0f};
    const f2v epsf = {EPS, EPS};

    const f2v gx  = pk_fma(two, b.hx, a.hx + c.hx);   // sobel_x (raw)
    const f2v gy  = c.hs - a.hs;                      // sobel_y (raw)
    const f2v tot = (a.rs + c.rs) + b.rs;             // 3x3 sum
    const f2v H   = (a.hs + c.hs) + b.hs;
    const f2v rxx = pk_fma(m3, H - tot, tot);         // k_xx * 3 (raw)
    const f2v tyy = pk_fma(m3, b.rs, tot);            // k_yy * 3 (raw)
    const f2v sxy = a.hx - c.hx;                      // k_xy * 4 (raw)

    const f2v gx2 = gx * gx, gy2 = gy * gy, gxgy = gx * gy;
    const f2v g2  = gx2 + gy2;
    const f2v d1  = A2f * g2;                         // p^2 + q^2
    const f2v od  = d1 + f2v{1.0f, 1.0f};

    f2v rsq_od, sq_d1;                                // per-component transcendentals
    rsq_od.x = __builtin_amdgcn_rsqf(od.x);
    rsq_od.y = __builtin_amdgcn_rsqf(od.y);
    sq_d1.x  = __builtin_amdgcn_sqrtf(d1.x);
    sq_d1.y  = __builtin_amdgcn_sqrtf(d1.y);
    const f2v sq_od = od * rsq_od;                    // sqrt(1+d1)

    const f2v h1    = pk_fma(tyy, gy2, rxx * gx2);
    const f2v h3    = pk_fma(tyy, gx2, rxx * gy2);
    const f2v h2c   = C2f * (sxy * gxgy);
    const f2v nprof = A2f * pk_fma(Bcf, h1,  h2c);    // r*p2+2s*pq+t*q2
    const f2v nplan = A2f * pk_fma(Bcf, h3, -h2c);    // r*q2-2s*pq+t*p2
    const f2v mnum  = pk_fma(Bcf, rxx + tyy, nplan);  // (1+q2)r-2pq*s+(1+p2)t

    const f2v den_p = pk_fma(d1, sq_od, epsf);        // d1*sqrt(1+d1)+EPS
    const f2v den_l = pk_fma(d1, sq_d1, epsf);        // d1^1.5+EPS
    const f2v plprod = den_p * den_l;                 // >=1e-16, no underflow
    f2v rcpPL;
    rcpPL.x = __builtin_amdgcn_rcpf(plprod.x);
    rcpPL.y = __builtin_amdgcn_rcpf(plprod.y);

    prof  = (nprof * den_l) * rcpPL;
    plan  = (nplan * den_p) * rcpPL;
    mean2 = mnum * ((rsq_od * rsq_od) * rsq_od);      // mnum/od^1.5 = 2*mean
    // flat mask per component
    prof.x = (d1.x < EPS) ? 0.0f : prof.x;
    prof.y = (d1.y < EPS) ? 0.0f : prof.y;
    plan.x = (d1.x < EPS) ? 0.0f : plan.x;
    plan.y = (d1.y < EPS) ? 0.0f : plan.y;
}

template<int MODE>
__device__ __forceinline__ float run_col(const char* __restrict__ Pc,
                                         const char* __restrict__ Tc,
                                         int y0, int cbyte, bool edge)
{
    Rowv w[3];
    float acc = 0.0f;

    // load row y (address clamped; value masked by vld) and push into window slot
    auto dorow = [&](int y, Rowv& o) {
        const int yc = y < 0 ? 0 : (y > IMG_H - 1 ? IMG_H - 1 : y);  // uniform
        const int vo = cbyte + (yc << 12);       // single offset VGPR
        const float pm = *(const float*)(Pc + vo);
        const float pc = *(const float*)(Pc + vo + 4);
        const float pp = *(const float*)(Pc + vo + 8);
        const float tm = *(const float*)(Tc + vo);
        const float tc = *(const float*)(Tc + vo + 4);
        const float tp = *(const float*)(Tc + vo + 8);
        basis<MODE>(pm, pc, pp, tm, tc, tp, (unsigned)y < (unsigned)IMG_H, edge, o);
    };

    dorow(y0 - 1, w[0]);
    dorow(y0,     w[1]);
#pragma unroll
    for (int i = 0; i < ROWS; ++i) {
        const int ia = i % 3, ib = (i + 1) % 3, ic = (i + 2) % 3;
        dorow(y0 + i + 1, w[ic]);
        f2v prof, plan, mean2;
        curv_pair(w[ia], w[ib], w[ic], prof, plan, mean2);
        acc = fmaf(0.5f, fabsf(prof.x  - prof.y),  acc);
        acc = fmaf(0.3f, fabsf(plan.x  - plan.y),  acc);
        acc = fmaf(0.1f, fabsf(mean2.x - mean2.y), acc);  // 0.2*|dMean|
    }
    return acc;
}

__global__ __launch_bounds__(BLOCK) void curv_loss_main(
    const float* __restrict__ pred, const float* __restrict__ targ,
    float* __restrict__ blocksums)
{
    const int tid = threadIdx.x;
    const int b   = blockIdx.x;
    const int tx  = b & (TILES_X - 1);
    const int ty  = (b >> 2) & (TILES_Y - 1);
    const int img = b >> 8;                   // 4*64 = 256 blocks per image
    const int y0  = ty * ROWS;
    const int x   = tx * BLOCK + tid;

    const size_t ibase = (size_t)img * (size_t)(IMG_H * IMG_W);
    const char* __restrict__ Pc = (const char*)(pred + ibase);
    const char* __restrict__ Tc = (const char*)(targ + ibase);

    int cb = x - 1;
    if (cb < 0) cb = 0;                        // lane x==0   (MODE0 edge)
    if (cb > IMG_W - 3) cb = IMG_W - 3;        // lane x==1023 (MODE2 edge)
    const int cbyte = cb << 2;
    const bool edge = (tx == 0) ? (tid == 0) : (tid == BLOCK - 1);

    float acc;
    if      (tx == 0)            acc = run_col<0>(Pc, Tc, y0, cbyte, edge);
    else if (tx == TILES_X - 1)  acc = run_col<2>(Pc, Tc, y0, cbyte, edge);
    else                         acc = run_col<1>(Pc, Tc, y0, cbyte, false);

    // wave64 reduce, then cross-wave via LDS
#pragma unroll
    for (int off = 32; off > 0; off >>= 1) acc += __shfl_down(acc, off, 64);
    __shared__ float ws[BLOCK / 64];
    const int lane = tid & 63, wid = tid >> 6;
    if (lane == 0) ws[wid] = acc;
    __syncthreads();
    if (tid == 0)
        blocksums[b] = (ws[0] + ws[1]) + (ws[2] + ws[3]);
}

__global__ __launch_bounds__(BLOCK) void curv_loss_final(
    const float* __restrict__ blocksums, float* __restrict__ out)
{
    const int tid = threadIdx.x;
    float v = 0.0f;
#pragma unroll
    for (int i = 0; i < NBLOCKS / BLOCK; ++i) v += blocksums[i * BLOCK + tid];
#pragma unroll
    for (int off = 32; off > 0; off >>= 1) v += __shfl_down(v, off, 64);
    __shared__ float ws[BLOCK / 64];
    const int lane = tid & 63, wid = tid >> 6;
    if (lane == 0) ws[wid] = v;
    __syncthreads();
    if (tid == 0) {
        const float tot = (ws[0] + ws[1]) + (ws[2] + ws[3]);
        out[0] = tot * (1.0f / (float)(IMG_B * IMG_H * IMG_W));
    }
}

extern "C" void kernel_launch(void* const* d_in, const int* in_sizes, int n_in,
                              void* d_out, int out_size, void* d_ws, size_t ws_size,
                              hipStream_t stream)
{
    const float* pred = (const float*)d_in[0];
    const float* targ = (const float*)d_in[1];
    float* out = (float*)d_out;
    float* blocksums = (float*)d_ws;   // 4096 floats; every slot written each call

    curv_loss_main<<<NBLOCKS, BLOCK, 0, stream>>>(pred, targ, blocksums);
    curv_loss_final<<<1, BLOCK, 0, stream>>>(blocksums, out);
}

// Round 10
// 158.690 us; speedup vs baseline: 1.1156x; 1.0027x over previous
//
#include <hip/hip_runtime.h>
#include <math.h>

// Problem: [16,1,1024,1024] fp32 pred/target -> scalar weighted mean-abs curvature loss.
// R10 = R9 with the unroll window controlled. R6..R9 all pinned at ~33us of issue
// volume; dur tracks latency hiding only (R7 vgpr64->57us, R9 vgpr84->59us,
// R8 vgpr84+pipe->78us). The VGPR hog is the FULL 16-row unroll: the compiler
// pipelines loads 2-3 iterations ahead -> ~84 VGPR every time. Fixes:
//  - ROWS 16->8, '#pragma unroll 2' -> hoist window = 2 iterations.
//  - explicit wa/wb/wc register rotation (w[i%3] under partial unroll = runtime
//    index = scratch).
//  - 8192 blocks for dispatch overlap.
// Numerics identical to R5..R9 (all absmax 0.0): reference EPS in den_p/den_l
// (R2 lesson), mean-denom EPS below half-ulp of 2 -> folded (0.2 -> 0.1),
// shared rcp(den_p*den_l). No min-waves bound (R4 spill lesson).

constexpr int IMG_B = 16;
constexpr int IMG_H = 1024;
constexpr int IMG_W = 1024;
constexpr int ROWS  = 8;                       // rows per block
constexpr int BLOCK = 256;                     // 256 threads = 256 columns
constexpr int TILES_X = IMG_W / BLOCK;         // 4
constexpr int TILES_Y = IMG_H / ROWS;          // 128
constexpr int NBLOCKS = IMG_B * TILES_Y * TILES_X;  // 8192
constexpr float EPS = 1e-8f;

// scale constants: p = gx/80, q = gy/80, r = rxx/300, 2s = sxy/200, t = tyy/300
constexpr float A2 = 1.0f / 6400.0f;
constexpr float Bc = 1.0f / 300.0f;
constexpr float C2 = 1.0f / 200.0f;

typedef float f2v __attribute__((ext_vector_type(2)));

__device__ __forceinline__ f2v pk_fma(f2v a, f2v b, f2v c) {
    return __builtin_elementwise_fma(a, b, c);
}

// rolling-window row state, lanes = {pred, target}
struct Rowv { f2v hx, hs, rs; };

// Taps loaded from clamped base column cb = clamp(x-1, 0, 1021):
//   interior lane: (m,c,p) = cols (x-1, x, x+1) directly.
//   MODE0 edge lane (x=0,    cb=0):    w0=0,        w1=v[0]=m,    w2=v[1]=c.
//   MODE2 edge lane (x=1023, cb=1021): w0=v[1022]=c, w1=v[1023]=p, w2=0.
template<int MODE>
__device__ __forceinline__ void basis(float pm, float pc, float pp,
                                      float tm, float tc, float tp,
                                      bool vld, bool edge, Rowv& o)
{
    if (vld) {                                  // block-uniform branch
        f2v w0, w1, w2;
        if (MODE == 0) {
            w0 = f2v{edge ? 0.0f : pm, edge ? 0.0f : tm};
            w1 = f2v{edge ? pm : pc,   edge ? tm : tc};
            w2 = f2v{edge ? pc : pp,   edge ? tc : tp};
        } else if (MODE == 2) {
            w0 = f2v{edge ? pc : pm,   edge ? tc : tm};
            w1 = f2v{edge ? pp : pc,   edge ? tp : tc};
            w2 = f2v{edge ? 0.0f : pp, edge ? 0.0f : tp};
        } else {
            w0 = f2v{pm, tm}; w1 = f2v{pc, tc}; w2 = f2v{pp, tp};
        }
        const f2v e = w0 + w2;
        o.hx = w2 - w0;
        o.hs = pk_fma(f2v{2.0f, 2.0f}, w1, e);
        o.rs = e + w1;
    } else {                                    // zero 'SAME' padding row
        o.hx = f2v{0.0f, 0.0f}; o.hs = f2v{0.0f, 0.0f}; o.rs = f2v{0.0f, 0.0f};
    }
}

// prof/plan true scale; mean2 = 2*mean (weight absorbs the 1/2). Lane-parallel
// over {pred, target}; transcendentals + flat-mask per-component.
__device__ __forceinline__ void curv_pair(const Rowv& a, const Rowv& b, const Rowv& c,
                                          f2v& prof, f2v& plan, f2v& mean2)
{
    const f2v A2f = {A2, A2}, Bcf = {Bc, Bc}, C2f = {C2, C2};
    const f2v m3  = {-3.0f, -3.0f}, two = {2.0f, 2.0f};
    const f2v epsf = {EPS, EPS};

    const f2v gx  = pk_fma(two, b.hx, a.hx + c.hx);   // sobel_x (raw)
    const f2v gy  = c.hs - a.hs;                      // sobel_y (raw)
    const f2v tot = (a.rs + c.rs) + b.rs;             // 3x3 sum
    const f2v H   = (a.hs + c.hs) + b.hs;
    const f2v rxx = pk_fma(m3, H - tot, tot);         // k_xx * 3 (raw)
    const f2v tyy = pk_fma(m3, b.rs, tot);            // k_yy * 3 (raw)
    const f2v sxy = a.hx - c.hx;                      // k_xy * 4 (raw)

    const f2v gx2 = gx * gx, gy2 = gy * gy, gxgy = gx * gy;
    const f2v g2  = gx2 + gy2;
    const f2v d1  = A2f * g2;                         // p^2 + q^2
    const f2v od  = d1 + f2v{1.0f, 1.0f};

    f2v rsq_od, sq_d1;                                // per-component transcendentals
    rsq_od.x = __builtin_amdgcn_rsqf(od.x);
    rsq_od.y = __builtin_amdgcn_rsqf(od.y);
    sq_d1.x  = __builtin_amdgcn_sqrtf(d1.x);
    sq_d1.y  = __builtin_amdgcn_sqrtf(d1.y);
    const f2v sq_od = od * rsq_od;                    // sqrt(1+d1)

    const f2v h1    = pk_fma(tyy, gy2, rxx * gx2);
    const f2v h3    = pk_fma(tyy, gx2, rxx * gy2);
    const f2v h2c   = C2f * (sxy * gxgy);
    const f2v nprof = A2f * pk_fma(Bcf, h1,  h2c);    // r*p2+2s*pq+t*q2
    const f2v nplan = A2f * pk_fma(Bcf, h3, -h2c);    // r*q2-2s*pq+t*p2
    const f2v mnum  = pk_fma(Bcf, rxx + tyy, nplan);  // (1+q2)r-2pq*s+(1+p2)t

    const f2v den_p = pk_fma(d1, sq_od, epsf);        // d1*sqrt(1+d1)+EPS
    const f2v den_l = pk_fma(d1, sq_d1, epsf);        // d1^1.5+EPS
    const f2v plprod = den_p * den_l;                 // >=1e-16, no underflow
    f2v rcpPL;
    rcpPL.x = __builtin_amdgcn_rcpf(plprod.x);
    rcpPL.y = __builtin_amdgcn_rcpf(plprod.y);

    prof  = (nprof * den_l) * rcpPL;
    plan  = (nplan * den_p) * rcpPL;
    mean2 = mnum * ((rsq_od * rsq_od) * rsq_od);      // mnum/od^1.5 = 2*mean
    // flat mask per component
    prof.x = (d1.x < EPS) ? 0.0f : prof.x;
    prof.y = (d1.y < EPS) ? 0.0f : prof.y;
    plan.x = (d1.x < EPS) ? 0.0f : plan.x;
    plan.y = (d1.y < EPS) ? 0.0f : plan.y;
}

template<int MODE>
__device__ __forceinline__ float run_col(const char* __restrict__ Pc,
                                         const char* __restrict__ Tc,
                                         int y0, int cbyte, bool edge)
{
    // load row y (address clamped; value masked by vld) and build basis
    auto dorow = [&](int y, Rowv& o) {
        const int yc = y < 0 ? 0 : (y > IMG_H - 1 ? IMG_H - 1 : y);  // uniform
        const int vo = cbyte + (yc << 12);       // single offset VGPR
        const float pm = *(const float*)(Pc + vo);
        const float pc = *(const float*)(Pc + vo + 4);
        const float pp = *(const float*)(Pc + vo + 8);
        const float tm = *(const float*)(Tc + vo);
        const float tc = *(const float*)(Tc + vo + 4);
        const float tp = *(const float*)(Tc + vo + 8);
        basis<MODE>(pm, pc, pp, tm, tc, tp, (unsigned)y < (unsigned)IMG_H, edge, o);
    };

    Rowv wa, wb, wc;
    dorow(y0 - 1, wa);
    dorow(y0,     wb);

    float acc = 0.0f;
#pragma unroll 2                               // cap the load-hoist window (VGPR!)
    for (int i = 0; i < ROWS; ++i) {
        dorow(y0 + i + 1, wc);
        f2v prof, plan, mean2;
        curv_pair(wa, wb, wc, prof, plan, mean2);
        acc = fmaf(0.5f, fabsf(prof.x  - prof.y),  acc);
        acc = fmaf(0.3f, fabsf(plan.x  - plan.y),  acc);
        acc = fmaf(0.1f, fabsf(mean2.x - mean2.y), acc);  // 0.2*|dMean|
        wa = wb; wb = wc;                       // register rotation (renamed, free)
    }
    return acc;
}

__global__ __launch_bounds__(BLOCK) void curv_loss_main(
    const float* __restrict__ pred, const float* __restrict__ targ,
    float* __restrict__ blocksums)
{
    const int tid = threadIdx.x;
    const int b   = blockIdx.x;
    const int tx  = b & (TILES_X - 1);
    const int ty  = (b >> 2) & (TILES_Y - 1);
    const int img = b >> 9;                   // 4*128 = 512 blocks per image
    const int y0  = ty * ROWS;
    const int x   = tx * BLOCK + tid;

    const size_t ibase = (size_t)img * (size_t)(IMG_H * IMG_W);
    const char* __restrict__ Pc = (const char*)(pred + ibase);
    const char* __restrict__ Tc = (const char*)(targ + ibase);

    int cb = x - 1;
    if (cb < 0) cb = 0;                        // lane x==0   (MODE0 edge)
    if (cb > IMG_W - 3) cb = IMG_W - 3;        // lane x==1023 (MODE2 edge)
    const int cbyte = cb << 2;
    const bool edge = (tx == 0) ? (tid == 0) : (tid == BLOCK - 1);

    float acc;
    if      (tx == 0)            acc = run_col<0>(Pc, Tc, y0, cbyte, edge);
    else if (tx == TILES_X - 1)  acc = run_col<2>(Pc, Tc, y0, cbyte, edge);
    else                         acc = run_col<1>(Pc, Tc, y0, cbyte, false);

    // wave64 reduce, then cross-wave via LDS
#pragma unroll
    for (int off = 32; off > 0; off >>= 1) acc += __shfl_down(acc, off, 64);
    __shared__ float ws[BLOCK / 64];
    const int lane = tid & 63, wid = tid >> 6;
    if (lane == 0) ws[wid] = acc;
    __syncthreads();
    if (tid == 0)
        blocksums[b] = (ws[0] + ws[1]) + (ws[2] + ws[3]);
}

__global__ __launch_bounds__(BLOCK) void curv_loss_final(
    const float* __restrict__ blocksums, float* __restrict__ out)
{
    const int tid = threadIdx.x;
    float v = 0.0f;
#pragma unroll
    for (int i = 0; i < NBLOCKS / BLOCK; ++i) v += blocksums[i * BLOCK + tid];
#pragma unroll
    for (int off = 32; off > 0; off >>= 1) v += __shfl_down(v, off, 64);
    __shared__ float ws[BLOCK / 64];
    const int lane = tid & 63, wid = tid >> 6;
    if (lane == 0) ws[wid] = v;
    __syncthreads();
    if (tid == 0) {
        const float tot = (ws[0] + ws[1]) + (ws[2] + ws[3]);
        out[0] = tot * (1.0f / (float)(IMG_B * IMG_H * IMG_W));
    }
}

extern "C" void kernel_launch(void* const* d_in, const int* in_sizes, int n_in,
                              void* d_out, int out_size, void* d_ws, size_t ws_size,
                              hipStream_t stream)
{
    const float* pred = (const float*)d_in[0];
    const float* targ = (const float*)d_in[1];
    float* out = (float*)d_out;
    float* blocksums = (float*)d_ws;   // 8192 floats = 32 KiB; every slot written

    curv_loss_main<<<NBLOCKS, BLOCK, 0, stream>>>(pred, targ, blocksums);
    curv_loss_final<<<1, BLOCK, 0, stream>>>(blocksums, out);
}

// Round 11
// 156.638 us; speedup vs baseline: 1.1302x; 1.0131x over previous
//
#include <hip/hip_runtime.h>
#include <math.h>

// Problem: [16,1,1024,1024] fp32 pred/target -> scalar weighted mean-abs curvature loss.
// R11 = R10's pressure fix (unroll 2 + explicit rotation -> VGPR 28) applied at
// ROWS=16 (halo 1.25x -> 1.125x, prologue amortized 2x), plus:
//  - barrier-free main: each wave writes blocksums[4b+wid]; no LDS/__syncthreads.
//  - A2 folded into the numerator constants (2 fewer pk muls per row-step).
// Cross-round model: VALU-cycle floor ~30-35us; occupancy beyond ~6 waves/SIMD
// doesn't raise VALUBusy (R7 33%occ/60% vs R10 68%occ/65%) -- cut cycles, not TLP.
// Numerics: same formulas as R5..R10 (all absmax 0.0): reference EPS in den_p/den_l
// (R2 lesson), mean-denom EPS below half-ulp of 2 -> folded (0.2 -> 0.1), shared
// rcp(den_p*den_l). No min-waves bound (R4 spill lesson).

constexpr int IMG_B = 16;
constexpr int IMG_H = 1024;
constexpr int IMG_W = 1024;
constexpr int ROWS  = 16;                      // rows per block
constexpr int BLOCK = 256;                     // 256 threads = 256 columns
constexpr int TILES_X = IMG_W / BLOCK;         // 4
constexpr int TILES_Y = IMG_H / ROWS;          // 64
constexpr int NBLOCKS = IMG_B * TILES_Y * TILES_X;  // 4096
constexpr int NSUMS   = NBLOCKS * 4;           // one partial per wave
constexpr float EPS = 1e-8f;

// scale constants: p = gx/80, q = gy/80, r = rxx/300, 2s = sxy/200, t = tyy/300
constexpr float A2 = 1.0f / 6400.0f;
constexpr float Bc = 1.0f / 300.0f;
constexpr float Bc2 = A2 * Bc;                 // folded numerator consts
constexpr float C22 = A2 * (1.0f / 200.0f);

typedef float f2v __attribute__((ext_vector_type(2)));

__device__ __forceinline__ f2v pk_fma(f2v a, f2v b, f2v c) {
    return __builtin_elementwise_fma(a, b, c);
}

// rolling-window row state, lanes = {pred, target}
struct Rowv { f2v hx, hs, rs; };

// Taps loaded from clamped base column cb = clamp(x-1, 0, 1021):
//   interior lane: (m,c,p) = cols (x-1, x, x+1) directly.
//   MODE0 edge lane (x=0,    cb=0):    w0=0,         w1=v[0]=m,    w2=v[1]=c.
//   MODE2 edge lane (x=1023, cb=1021): w0=v[1022]=c, w1=v[1023]=p, w2=0.
template<int MODE>
__device__ __forceinline__ void basis(float pm, float pc, float pp,
                                      float tm, float tc, float tp,
                                      bool vld, bool edge, Rowv& o)
{
    if (vld) {                                  // block-uniform branch
        f2v w0, w1, w2;
        if (MODE == 0) {
            w0 = f2v{edge ? 0.0f : pm, edge ? 0.0f : tm};
            w1 = f2v{edge ? pm : pc,   edge ? tm : tc};
            w2 = f2v{edge ? pc : pp,   edge ? tc : tp};
        } else if (MODE == 2) {
            w0 = f2v{edge ? pc : pm,   edge ? tc : tm};
            w1 = f2v{edge ? pp : pc,   edge ? tp : tc};
            w2 = f2v{edge ? 0.0f : pp, edge ? 0.0f : tp};
        } else {
            w0 = f2v{pm, tm}; w1 = f2v{pc, tc}; w2 = f2v{pp, tp};
        }
        const f2v e = w0 + w2;
        o.hx = w2 - w0;
        o.hs = pk_fma(f2v{2.0f, 2.0f}, w1, e);
        o.rs = e + w1;
    } else {                                    // zero 'SAME' padding row
        o.hx = f2v{0.0f, 0.0f}; o.hs = f2v{0.0f, 0.0f}; o.rs = f2v{0.0f, 0.0f};
    }
}

// prof/plan true scale; mean2 = 2*mean (weight absorbs the 1/2). Lane-parallel
// over {pred, target}; transcendentals + flat-mask per-component.
__device__ __forceinline__ void curv_pair(const Rowv& a, const Rowv& b, const Rowv& c,
                                          f2v& prof, f2v& plan, f2v& mean2)
{
    const f2v A2f = {A2, A2}, Bcf = {Bc, Bc}, Bc2f = {Bc2, Bc2}, C22f = {C22, C22};
    const f2v m3  = {-3.0f, -3.0f}, two = {2.0f, 2.0f};
    const f2v epsf = {EPS, EPS};

    const f2v gx  = pk_fma(two, b.hx, a.hx + c.hx);   // sobel_x (raw)
    const f2v gy  = c.hs - a.hs;                      // sobel_y (raw)
    const f2v tot = (a.rs + c.rs) + b.rs;             // 3x3 sum
    const f2v H   = (a.hs + c.hs) + b.hs;
    const f2v rxx = pk_fma(m3, H - tot, tot);         // k_xx * 3 (raw)
    const f2v tyy = pk_fma(m3, b.rs, tot);            // k_yy * 3 (raw)
    const f2v sxy = a.hx - c.hx;                      // k_xy * 4 (raw)

    const f2v gx2 = gx * gx, gy2 = gy * gy, gxgy = gx * gy;
    const f2v g2  = gx2 + gy2;
    const f2v d1  = A2f * g2;                         // p^2 + q^2
    const f2v od  = d1 + f2v{1.0f, 1.0f};

    f2v rsq_od, sq_d1;                                // per-component transcendentals
    rsq_od.x = __builtin_amdgcn_rsqf(od.x);
    rsq_od.y = __builtin_amdgcn_rsqf(od.y);
    sq_d1.x  = __builtin_amdgcn_sqrtf(d1.x);
    sq_d1.y  = __builtin_amdgcn_sqrtf(d1.y);
    const f2v sq_od = od * rsq_od;                    // sqrt(1+d1)

    const f2v h1    = pk_fma(tyy, gy2, rxx * gx2);
    const f2v h3    = pk_fma(tyy, gx2, rxx * gy2);
    const f2v h2c   = C22f * (sxy * gxgy);            // A2*C2*(sxy*gxgy)
    const f2v nprof = pk_fma(Bc2f, h1,  h2c);         // true r*p2+2s*pq+t*q2
    const f2v nplan = pk_fma(Bc2f, h3, -h2c);         // true r*q2-2s*pq+t*p2
    const f2v mnum  = pk_fma(Bcf, rxx + tyy, nplan);  // (1+q2)r-2pq*s+(1+p2)t

    const f2v den_p = pk_fma(d1, sq_od, epsf);        // d1*sqrt(1+d1)+EPS
    const f2v den_l = pk_fma(d1, sq_d1, epsf);        // d1^1.5+EPS
    const f2v plprod = den_p * den_l;                 // >=1e-16, no underflow
    f2v rcpPL;
    rcpPL.x = __builtin_amdgcn_rcpf(plprod.x);
    rcpPL.y = __builtin_amdgcn_rcpf(plprod.y);

    prof  = (nprof * den_l) * rcpPL;
    plan  = (nplan * den_p) * rcpPL;
    mean2 = mnum * ((rsq_od * rsq_od) * rsq_od);      // mnum/od^1.5 = 2*mean
    // flat mask per component
    prof.x = (d1.x < EPS) ? 0.0f : prof.x;
    prof.y = (d1.y < EPS) ? 0.0f : prof.y;
    plan.x = (d1.x < EPS) ? 0.0f : plan.x;
    plan.y = (d1.y < EPS) ? 0.0f : plan.y;
}

template<int MODE>
__device__ __forceinline__ float run_col(const char* __restrict__ Pc,
                                         const char* __restrict__ Tc,
                                         int y0, int cbyte, bool edge)
{
    // load row y (address clamped; value masked by vld) and build basis
    auto dorow = [&](int y, Rowv& o) {
        const int yc = y < 0 ? 0 : (y > IMG_H - 1 ? IMG_H - 1 : y);  // uniform
        const int vo = cbyte + (yc << 12);       // single offset VGPR
        const float pm = *(const float*)(Pc + vo);
        const float pc = *(const float*)(Pc + vo + 4);
        const float pp = *(const float*)(Pc + vo + 8);
        const float tm = *(const float*)(Tc + vo);
        const float tc = *(const float*)(Tc + vo + 4);
        const float tp = *(const float*)(Tc + vo + 8);
        basis<MODE>(pm, pc, pp, tm, tc, tp, (unsigned)y < (unsigned)IMG_H, edge, o);
    };

    Rowv wa, wb, wc;
    dorow(y0 - 1, wa);
    dorow(y0,     wb);

    float acc = 0.0f;
#pragma unroll 2                               // cap the load-hoist window (VGPR!)
    for (int i = 0; i < ROWS; ++i) {
        dorow(y0 + i + 1, wc);
        f2v prof, plan, mean2;
        curv_pair(wa, wb, wc, prof, plan, mean2);
        acc = fmaf(0.5f, fabsf(prof.x  - prof.y),  acc);
        acc = fmaf(0.3f, fabsf(plan.x  - plan.y),  acc);
        acc = fmaf(0.1f, fabsf(mean2.x - mean2.y), acc);  // 0.2*|dMean|
        wa = wb; wb = wc;                       // register rotation (renamed, free)
    }
    return acc;
}

__global__ __launch_bounds__(BLOCK) void curv_loss_main(
    const float* __restrict__ pred, const float* __restrict__ targ,
    float* __restrict__ blocksums)
{
    const int tid = threadIdx.x;
    const int b   = blockIdx.x;
    const int tx  = b & (TILES_X - 1);
    const int ty  = (b >> 2) & (TILES_Y - 1);
    const int img = b >> 8;                   // 4*64 = 256 blocks per image
    const int y0  = ty * ROWS;
    const int x   = tx * BLOCK + tid;

    const size_t ibase = (size_t)img * (size_t)(IMG_H * IMG_W);
    const char* __restrict__ Pc = (const char*)(pred + ibase);
    const char* __restrict__ Tc = (const char*)(targ + ibase);

    int cb = x - 1;
    if (cb < 0) cb = 0;                        // lane x==0   (MODE0 edge)
    if (cb > IMG_W - 3) cb = IMG_W - 3;        // lane x==1023 (MODE2 edge)
    const int cbyte = cb << 2;
    const bool edge = (tx == 0) ? (tid == 0) : (tid == BLOCK - 1);

    float acc;
    if      (tx == 0)            acc = run_col<0>(Pc, Tc, y0, cbyte, edge);
    else if (tx == TILES_X - 1)  acc = run_col<2>(Pc, Tc, y0, cbyte, edge);
    else                         acc = run_col<1>(Pc, Tc, y0, cbyte, false);

    // wave64 reduce; each wave writes its own partial -- no LDS, no barrier
#pragma unroll
    for (int off = 32; off > 0; off >>= 1) acc += __shfl_down(acc, off, 64);
    const int lane = tid & 63, wid = tid >> 6;
    if (lane == 0) blocksums[(b << 2) + wid] = acc;
}

__global__ __launch_bounds__(BLOCK) void curv_loss_final(
    const float* __restrict__ blocksums, float* __restrict__ out)
{
    const int tid = threadIdx.x;
    float v = 0.0f;
#pragma unroll
    for (int i = 0; i < NSUMS / BLOCK; ++i) v += blocksums[i * BLOCK + tid];
#pragma unroll
    for (int off = 32; off > 0; off >>= 1) v += __shfl_down(v, off, 64);
    __shared__ float ws[BLOCK / 64];
    const int lane = tid & 63, wid = tid >> 6;
    if (lane == 0) ws[wid] = v;
    __syncthreads();
    if (tid == 0) {
        const float tot = (ws[0] + ws[1]) + (ws[2] + ws[3]);
        out[0] = tot * (1.0f / (float)(IMG_B * IMG_H * IMG_W));
    }
}

extern "C" void kernel_launch(void* const* d_in, const int* in_sizes, int n_in,
                              void* d_out, int out_size, void* d_ws, size_t ws_size,
                              hipStream_t stream)
{
    const float* pred = (const float*)d_in[0];
    const float* targ = (const float*)d_in[1];
    float* out = (float*)d_out;
    float* blocksums = (float*)d_ws;   // 16384 floats = 64 KiB; every slot written

    curv_loss_main<<<NBLOCKS, BLOCK, 0, stream>>>(pred, targ, blocksums);
    curv_loss_final<<<1, BLOCK, 0, stream>>>(blocksums, out);
}